// Round 3
// baseline (486.419 us; speedup 1.0000x reference)
//
#include <hip/hip_runtime.h>
#include <hip/hip_bf16.h>
#include <stdint.h>

// Problem constants (fixed by the reference).
#define B_SZ 16384
#define K_SZ 5
#define H_SZ 512
#define E_SZ 512

typedef _Float16 f16;
typedef _Float16 f16x8 __attribute__((ext_vector_type(8)));
typedef float    f32x4 __attribute__((ext_vector_type(4)));

// ---------------------------------------------------------------------------
// async global->LDS, 16B per lane (gfx950). LDS dest must be wave-uniform
// base + lane*16.
__device__ __forceinline__ void gload_lds16(const void* g, void* l) {
  __builtin_amdgcn_global_load_lds(
      (const __attribute__((address_space(1))) unsigned int*)g,
      (__attribute__((address_space(3))) unsigned int*)l, 16, 0, 0);
}

// ---------------------------------------------------------------------------
// fp32 -> fp16 conversion, 8 elems/thread, vectorized.
__global__ __launch_bounds__(256) void cvt_kernel(const float* __restrict__ src,
                                                  f16* __restrict__ dst, int n8) {
  int i = blockIdx.x * 256 + threadIdx.x;
  if (i >= n8) return;
  size_t o = (size_t)i * 8;
  float4 a = *(const float4*)(src + o);
  float4 b = *(const float4*)(src + o + 4);
  union { f16 h[8]; uint4 u; } u;
  u.h[0] = (f16)a.x; u.h[1] = (f16)a.y; u.h[2] = (f16)a.z; u.h[3] = (f16)a.w;
  u.h[4] = (f16)b.x; u.h[5] = (f16)b.y; u.h[6] = (f16)b.z; u.h[7] = (f16)b.w;
  *(uint4*)(dst + o) = u.u;
}

// One kernel preps all weights: Wa->f16 (into Wbig block 0), Ua->f16,
// Wa^T->f16 (LDS-tiled transpose). Grid = 512 blocks of 256.
__global__ __launch_bounds__(256)
void prep_weights(const float* __restrict__ Wa, const float* __restrict__ Ua,
                  f16* __restrict__ Wbig0, f16* __restrict__ Ua_h,
                  f16* __restrict__ WaT) {
  const int t = threadIdx.x;
  int bb = blockIdx.x;
  if (bb < 128) {                      // cvt Wa -> Wbig block 0
    size_t o = ((size_t)bb * 256 + t) * 8;
    float4 a = *(const float4*)(Wa + o);
    float4 b = *(const float4*)(Wa + o + 4);
    union { f16 h[8]; uint4 u; } u;
    u.h[0] = (f16)a.x; u.h[1] = (f16)a.y; u.h[2] = (f16)a.z; u.h[3] = (f16)a.w;
    u.h[4] = (f16)b.x; u.h[5] = (f16)b.y; u.h[6] = (f16)b.z; u.h[7] = (f16)b.w;
    *(uint4*)(Wbig0 + o) = u.u;
  } else if (bb < 256) {               // cvt Ua -> Ua_h
    size_t o = ((size_t)(bb - 128) * 256 + t) * 8;
    float4 a = *(const float4*)(Ua + o);
    float4 b = *(const float4*)(Ua + o + 4);
    union { f16 h[8]; uint4 u; } u;
    u.h[0] = (f16)a.x; u.h[1] = (f16)a.y; u.h[2] = (f16)a.z; u.h[3] = (f16)a.w;
    u.h[4] = (f16)b.x; u.h[5] = (f16)b.y; u.h[6] = (f16)b.z; u.h[7] = (f16)b.w;
    *(uint4*)(Ua_h + o) = u.u;
  } else {                             // transpose Wa -> WaT (f16)
    __shared__ float tile[32][33];
    int blk = bb - 256;                // 256 blocks = 16x16 tiles of 32x32
    int bx = blk & 15, by = blk >> 4;
    int tx = t & 31, ty = t >> 5;      // 32x8
    #pragma unroll
    for (int i = 0; i < 32; i += 8)
      tile[ty + i][tx] = Wa[(size_t)(by * 32 + ty + i) * 512 + bx * 32 + tx];
    __syncthreads();
    #pragma unroll
    for (int i = 0; i < 32; i += 8)
      WaT[(size_t)(bx * 32 + ty + i) * 512 + by * 32 + tx] =
          (f16)tile[tx][ty + i];
  }
}

// ---------------------------------------------------------------------------
// Y[m,n] (f16, pitch ldY) = sum_k A[m,k] * W[n,k].   K = 512 fixed.
// N = nTn*128 column tiles. W: f16 row-major [N x 512] (row = output col n).
// A: f16 (pitch ldA) staged via global_load_lds, or f32 converted in-register.
// 128x128 tile, BK=32, 256 threads = 4 waves (2x2), wave tile 64x64.
// XCD-aware bijective swizzle when gridDim%8==0: consecutive N-tiles of one
// M-tile land on the same XCD -> A-tile L2 reuse.
template <bool A_F32>
__global__ __launch_bounds__(256)
void gemm_bt(const void* __restrict__ Aop, const f16* __restrict__ W,
             f16* __restrict__ Y, int ldA, int ldY, int nTn) {
  __shared__ f16 As[128 * 32];
  __shared__ f16 Bs[128 * 32];
  const int t = threadIdx.x;
  const int l = t & 63, wid = t >> 6;
  const int wm = wid >> 1, wn = wid & 1;
  int bid = blockIdx.x;
  const int nwg = gridDim.x;
  if ((nwg & 7) == 0) bid = (bid & 7) * (nwg >> 3) + (bid >> 3);
  const int n0 = (bid % nTn) * 128;
  const size_t m0 = (size_t)(bid / nTn) * 128;
  const int lrow = l & 15;                // fragment row/col within 16
  const int lk = (l >> 4) * 8;            // fragment k-offset (8 f16)

  f32x4 acc[4][4] = {};

  for (int k0 = 0; k0 < 512; k0 += 32) {
    // ---- stage B tile (f16 always): 128 rows x 64B
    #pragma unroll
    for (int p = 0; p < 2; ++p) {
      int c = p * 256 + t;                // 16B chunk id, 0..511
      int row = c >> 2, seg = c & 3;
      gload_lds16(W + (size_t)(n0 + row) * 512 + k0 + seg * 8,
                  (char*)Bs + c * 16);
    }
    // ---- stage A tile
    if constexpr (!A_F32) {
      const f16* A = (const f16*)Aop;
      #pragma unroll
      for (int p = 0; p < 2; ++p) {
        int c = p * 256 + t;
        int row = c >> 2, seg = c & 3;
        gload_lds16(A + (m0 + row) * (size_t)ldA + k0 + seg * 8,
                    (char*)As + c * 16);
      }
    } else {
      const float* A = (const float*)Aop;
      #pragma unroll
      for (int p = 0; p < 4; ++p) {
        int c = p * 256 + t;              // float4 chunk id, 0..1023
        int row = c >> 3, seg = c & 7;
        const float4 v =
            *(const float4*)(A + (m0 + row) * (size_t)ldA + k0 + seg * 4);
        union { f16 h[4]; uint2 u; } cv;
        cv.h[0] = (f16)v.x; cv.h[1] = (f16)v.y;
        cv.h[2] = (f16)v.z; cv.h[3] = (f16)v.w;
        *(uint2*)((char*)As + row * 64 + seg * 8) = cv.u;
      }
    }
    __syncthreads();  // drains vmcnt (global_load_lds) + lgkmcnt (ds_write)

    f16x8 af[4], bf[4];
    #pragma unroll
    for (int mi = 0; mi < 4; ++mi)
      af[mi] = *(const f16x8*)(As + (wm * 64 + mi * 16 + lrow) * 32 + lk);
    #pragma unroll
    for (int ni = 0; ni < 4; ++ni)
      bf[ni] = *(const f16x8*)(Bs + (wn * 64 + ni * 16 + lrow) * 32 + lk);
    #pragma unroll
    for (int mi = 0; mi < 4; ++mi)
      #pragma unroll
      for (int ni = 0; ni < 4; ++ni)
        acc[mi][ni] = __builtin_amdgcn_mfma_f32_16x16x32_f16(
            af[mi], bf[ni], acc[mi][ni], 0, 0, 0);
    __syncthreads();
  }

  // epilogue: C/D layout col = lane&15, row = (lane>>4)*4 + j  [m89-verified]
  #pragma unroll
  for (int mi = 0; mi < 4; ++mi) {
    #pragma unroll
    for (int j = 0; j < 4; ++j) {
      size_t row = m0 + wm * 64 + mi * 16 + ((l >> 4) << 2) + j;
      #pragma unroll
      for (int ni = 0; ni < 4; ++ni) {
        int col = n0 + wn * 64 + ni * 16 + lrow;
        Y[row * (size_t)ldY + col] = (f16)acc[mi][ni][j];
      }
    }
  }
}

// ---------------------------------------------------------------------------
__device__ __forceinline__ float fast_tanh(float x) {
  float e = __expf(-2.f * fabsf(x));      // in (0,1], no overflow
  float r = (1.f - e) / (1.f + e);
  return copysignf(r, x);
}

// scores -> softmax -> mt, one wave per b row.
__device__ __forceinline__ void softmax_mt_dev(size_t b, int l, const float* s,
                                               const float* __restrict__ topics,
                                               float* __restrict__ out) {
  float m = s[0];
  #pragma unroll
  for (int k = 1; k < K_SZ; ++k) m = fmaxf(m, s[k]);
  float a[K_SZ], d = 0.f;
  #pragma unroll
  for (int k = 0; k < K_SZ; ++k) { a[k] = __expf(s[k] - m); d += a[k]; }
  float inv = 1.f / d;
  #pragma unroll
  for (int k = 0; k < K_SZ; ++k) a[k] *= inv;

  float acc0[4] = {}, acc1[4] = {};
  #pragma unroll
  for (int k = 0; k < K_SZ; ++k) {
    const float* tp = topics + (b * K_SZ + k) * E_SZ + l * 8;
    float4 t0 = *(const float4*)tp;
    float4 t1 = *(const float4*)(tp + 4);
    acc0[0] += a[k] * t0.x; acc0[1] += a[k] * t0.y;
    acc0[2] += a[k] * t0.z; acc0[3] += a[k] * t0.w;
    acc1[0] += a[k] * t1.x; acc1[1] += a[k] * t1.y;
    acc1[2] += a[k] * t1.z; acc1[3] += a[k] * t1.w;
  }
  float* mo = out + b * E_SZ + l * 8;
  *(float4*)mo       = make_float4(acc0[0], acc0[1], acc0[2], acc0[3]);
  *(float4*)(mo + 4) = make_float4(acc1[0], acc1[1], acc1[2], acc1[3]);
  if (l < K_SZ) {
    float av = (l == 0) ? a[0] : (l == 1) ? a[1] : (l == 2) ? a[2]
               : (l == 3) ? a[3] : a[4];
    out[(size_t)B_SZ * E_SZ + b * K_SZ + l] = av;
  }
}

// full pk [B*K, 512] materialized. One wave per b-row.
__global__ __launch_bounds__(256)
void finalize_full(const f16* __restrict__ qall, const f16* __restrict__ pk,
                   const float* __restrict__ topics, const float* __restrict__ cov,
                   const float* __restrict__ va_w, const float* __restrict__ va_b,
                   float* __restrict__ out) {
  const int wid = threadIdx.x >> 6, l = threadIdx.x & 63;
  const size_t b = (size_t)blockIdx.x * 4 + wid;
  const float vb = va_b[0];
  float va[8];
  *(float4*)(va)     = *(const float4*)(va_w + l * 8);
  *(float4*)(va + 4) = *(const float4*)(va_w + l * 8 + 4);

  float s[K_SZ];
  #pragma unroll
  for (int k = 0; k < K_SZ; ++k) {
    const size_t r = (b * K_SZ + k) * 512 + l * 8;
    f16x8 qv = *(const f16x8*)(qall + r);
    f16x8 pv = *(const f16x8*)(pk + r);
    float part = 0.f;
    #pragma unroll
    for (int j = 0; j < 8; ++j)
      part += va[j] * fast_tanh((float)qv[j] + (float)pv[j]);
    #pragma unroll
    for (int off = 32; off > 0; off >>= 1) part += __shfl_xor(part, off);
    s[k] = (part + vb) * cov[b * K_SZ + k];
  }
  softmax_mt_dev(b, l, s, topics, out);
}

// ---------------------------------------------------------------------------
extern "C" void kernel_launch(void* const* d_in, const int* in_sizes, int n_in,
                              void* d_out, int out_size, void* d_ws, size_t ws_size,
                              hipStream_t stream) {
  const float* query  = (const float*)d_in[0];
  const float* topics = (const float*)d_in[1];
  const float* cov    = (const float*)d_in[2];
  const float* Ua     = (const float*)d_in[3];
  const float* Wa     = (const float*)d_in[4];
  const float* va_w   = (const float*)d_in[5];
  const float* va_b   = (const float*)d_in[6];
  float* out = (float*)d_out;

  char* ws = (char*)d_ws;
  size_t off = 0;
  auto alloc = [&](size_t bytes) -> char* {
    char* p = ws + off;
    off += (bytes + 255) & ~(size_t)255;
    return p;
  };
  f16* q0h  = (f16*)alloc((size_t)B_SZ * H_SZ * 2);              // 16.8 MB
  f16* qall = (f16*)alloc((size_t)B_SZ * K_SZ * H_SZ * 2);       // 83.9 MB
  f16* Ua_h = (f16*)alloc((size_t)H_SZ * E_SZ * 2);              // 0.5 MB
  f16* WaT  = (f16*)alloc((size_t)H_SZ * H_SZ * 2);              // 0.5 MB
  f16* Wbig = (f16*)alloc((size_t)K_SZ * H_SZ * H_SZ * 2);       // 2.6 MB  P1..P5
  f16* pk   = (f16*)alloc((size_t)B_SZ * K_SZ * H_SZ * 2);       // 83.9 MB

  // prep: Wa->f16 (Wbig block 0 = P1), Ua->f16, Wa^T->f16
  prep_weights<<<512, 256, 0, stream>>>(Wa, Ua, Wbig, Ua_h, WaT);
  // query -> f16
  cvt_kernel<<<B_SZ * H_SZ / 8 / 256, 256, 0, stream>>>(query, q0h,
                                                        B_SZ * H_SZ / 8);
  // P_{j+1} = P_j @ Wa  (gemm_bt: Y = A @ WaT^T = A @ Wa), f16, 16 blocks each
  for (int j = 1; j < K_SZ; ++j)
    gemm_bt<false><<<16, 256, 0, stream>>>(
        Wbig + (size_t)(j - 1) * H_SZ * H_SZ, WaT,
        Wbig + (size_t)j * H_SZ * H_SZ, H_SZ, H_SZ, 4);
  // all five q_i in one GEMM: qall[b, i*512+h] = sum_k q0[b,k] * P_{i+1}[h,k]
  gemm_bt<false><<<(B_SZ / 128) * (K_SZ * H_SZ / 128), 256, 0, stream>>>(
      q0h, Wbig, qall, H_SZ, K_SZ * H_SZ, K_SZ * H_SZ / 128);
  // pk[bk, h] = sum_e topics[bk, e] * Ua[h, e]
  gemm_bt<true><<<(B_SZ * K_SZ / 128) * (H_SZ / 128), 256, 0, stream>>>(
      topics, Ua_h, pk, E_SZ, H_SZ, H_SZ / 128);
  // scores + softmax + mt
  finalize_full<<<B_SZ / 4, 256, 0, stream>>>(qall, pk, topics, cov, va_w,
                                              va_b, out);
}

// Round 4
// 464.501 us; speedup vs baseline: 1.0472x; 1.0472x over previous
//
#include <hip/hip_runtime.h>
#include <hip/hip_bf16.h>
#include <stdint.h>

// Problem constants (fixed by the reference).
#define B_SZ 16384
#define K_SZ 5
#define H_SZ 512
#define E_SZ 512

typedef _Float16 f16;
typedef _Float16 f16x8 __attribute__((ext_vector_type(8)));
typedef float    f32x4 __attribute__((ext_vector_type(4)));

// ---------------------------------------------------------------------------
// async global->LDS, 16B per lane (gfx950). LDS dest must be wave-uniform
// base + lane*16.
__device__ __forceinline__ void gload_lds16(const void* g, void* l) {
  __builtin_amdgcn_global_load_lds(
      (const __attribute__((address_space(1))) unsigned int*)g,
      (__attribute__((address_space(3))) unsigned int*)l, 16, 0, 0);
}

// ---------------------------------------------------------------------------
// fp32 -> fp16 conversion, 8 elems/thread, vectorized.
__global__ __launch_bounds__(256) void cvt_kernel(const float* __restrict__ src,
                                                  f16* __restrict__ dst, int n8) {
  int i = blockIdx.x * 256 + threadIdx.x;
  if (i >= n8) return;
  size_t o = (size_t)i * 8;
  float4 a = *(const float4*)(src + o);
  float4 b = *(const float4*)(src + o + 4);
  union { f16 h[8]; uint4 u; } u;
  u.h[0] = (f16)a.x; u.h[1] = (f16)a.y; u.h[2] = (f16)a.z; u.h[3] = (f16)a.w;
  u.h[4] = (f16)b.x; u.h[5] = (f16)b.y; u.h[6] = (f16)b.z; u.h[7] = (f16)b.w;
  *(uint4*)(dst + o) = u.u;
}

// One kernel preps all weights: Wa->f16 (into Wbig block 0), Ua->f16,
// Wa^T->f16 (LDS-tiled transpose). Grid = 512 blocks of 256.
__global__ __launch_bounds__(256)
void prep_weights(const float* __restrict__ Wa, const float* __restrict__ Ua,
                  f16* __restrict__ Wbig0, f16* __restrict__ Ua_h,
                  f16* __restrict__ WaT) {
  const int t = threadIdx.x;
  int bb = blockIdx.x;
  if (bb < 128) {                      // cvt Wa -> Wbig block 0
    size_t o = ((size_t)bb * 256 + t) * 8;
    float4 a = *(const float4*)(Wa + o);
    float4 b = *(const float4*)(Wa + o + 4);
    union { f16 h[8]; uint4 u; } u;
    u.h[0] = (f16)a.x; u.h[1] = (f16)a.y; u.h[2] = (f16)a.z; u.h[3] = (f16)a.w;
    u.h[4] = (f16)b.x; u.h[5] = (f16)b.y; u.h[6] = (f16)b.z; u.h[7] = (f16)b.w;
    *(uint4*)(Wbig0 + o) = u.u;
  } else if (bb < 256) {               // cvt Ua -> Ua_h
    size_t o = ((size_t)(bb - 128) * 256 + t) * 8;
    float4 a = *(const float4*)(Ua + o);
    float4 b = *(const float4*)(Ua + o + 4);
    union { f16 h[8]; uint4 u; } u;
    u.h[0] = (f16)a.x; u.h[1] = (f16)a.y; u.h[2] = (f16)a.z; u.h[3] = (f16)a.w;
    u.h[4] = (f16)b.x; u.h[5] = (f16)b.y; u.h[6] = (f16)b.z; u.h[7] = (f16)b.w;
    *(uint4*)(Ua_h + o) = u.u;
  } else {                             // transpose Wa -> WaT (f16)
    __shared__ float tile[32][33];
    int blk = bb - 256;                // 256 blocks = 16x16 tiles of 32x32
    int bx = blk & 15, by = blk >> 4;
    int tx = t & 31, ty = t >> 5;      // 32x8
    #pragma unroll
    for (int i = 0; i < 32; i += 8)
      tile[ty + i][tx] = Wa[(size_t)(by * 32 + ty + i) * 512 + bx * 32 + tx];
    __syncthreads();
    #pragma unroll
    for (int i = 0; i < 32; i += 8)
      WaT[(size_t)(bx * 32 + ty + i) * 512 + by * 32 + tx] =
          (f16)tile[tx][ty + i];
  }
}

// ---------------------------------------------------------------------------
// Small GEMM for the Wa-power chain: Y[m,n] = sum_k A[m,k]*W[n,k], K=512.
// 128x128 tile, BK=32, 4 waves. Used only for 512x512 matrices (grid 16).
__global__ __launch_bounds__(256)
void gemm_bt(const f16* __restrict__ A, const f16* __restrict__ W,
             f16* __restrict__ Y, int ldA, int ldY, int nTn) {
  __shared__ f16 As[128 * 32];
  __shared__ f16 Bs[128 * 32];
  const int t = threadIdx.x;
  const int l = t & 63, wid = t >> 6;
  const int wm = wid >> 1, wn = wid & 1;
  int bid = blockIdx.x;
  const int nwg = gridDim.x;
  if ((nwg & 7) == 0) bid = (bid & 7) * (nwg >> 3) + (bid >> 3);
  const int n0 = (bid % nTn) * 128;
  const size_t m0 = (size_t)(bid / nTn) * 128;
  const int lrow = l & 15;
  const int lk = (l >> 4) * 8;

  f32x4 acc[4][4] = {};

  for (int k0 = 0; k0 < 512; k0 += 32) {
    #pragma unroll
    for (int p = 0; p < 2; ++p) {
      int c = p * 256 + t;
      int row = c >> 2, seg = c & 3;
      gload_lds16(W + (size_t)(n0 + row) * 512 + k0 + seg * 8,
                  (char*)Bs + c * 16);
      gload_lds16(A + (m0 + row) * (size_t)ldA + k0 + seg * 8,
                  (char*)As + c * 16);
    }
    __syncthreads();

    f16x8 af[4], bf[4];
    #pragma unroll
    for (int mi = 0; mi < 4; ++mi)
      af[mi] = *(const f16x8*)(As + (wm * 64 + mi * 16 + lrow) * 32 + lk);
    #pragma unroll
    for (int ni = 0; ni < 4; ++ni)
      bf[ni] = *(const f16x8*)(Bs + (wn * 64 + ni * 16 + lrow) * 32 + lk);
    #pragma unroll
    for (int mi = 0; mi < 4; ++mi)
      #pragma unroll
      for (int ni = 0; ni < 4; ++ni)
        acc[mi][ni] = __builtin_amdgcn_mfma_f32_16x16x32_f16(
            af[mi], bf[ni], acc[mi][ni], 0, 0, 0);
    __syncthreads();
  }

  #pragma unroll
  for (int mi = 0; mi < 4; ++mi) {
    #pragma unroll
    for (int j = 0; j < 4; ++j) {
      size_t row = m0 + wm * 64 + mi * 16 + ((l >> 4) << 2) + j;
      #pragma unroll
      for (int ni = 0; ni < 4; ++ni) {
        int col = n0 + wn * 64 + ni * 16 + lrow;
        Y[row * (size_t)ldY + col] = (f16)acc[mi][ni][j];
      }
    }
  }
}

// ---------------------------------------------------------------------------
__device__ __forceinline__ float fast_tanh(float x) {
  float e = __expf(-2.f * fabsf(x));      // in (0,1], no overflow
  float r = (1.f - e) / (1.f + e);
  return copysignf(r, x);
}

// ---------------------------------------------------------------------------
// Fused: X[b,k,h] = sum_e topics[b,k,e]*Ua[h,e] + sum_c q0[b,c]*P_k[h,c]
// (K=1024 concat GEMM), then partial score over this block's 128 h-cols:
//   partials[nt*2+wn][k][b] = sum_h va[h]*tanh(X[b,k,h])
// Grid: 5 k-slices x 128 m-tiles x 4 n-tiles = 2560 blocks, XCD-swizzled.
__global__ __launch_bounds__(256)
void fused_score_gemm(const float* __restrict__ topics,
                      const f16* __restrict__ q0h,
                      const f16* __restrict__ Ua_h,
                      const f16* __restrict__ Wbig,
                      const float* __restrict__ va_w,
                      float* __restrict__ partials) {
  __shared__ f16 As[128 * 32];
  __shared__ f16 Bs[128 * 32];
  const int t = threadIdx.x;
  const int l = t & 63, wid = t >> 6;
  const int wm = wid >> 1, wn = wid & 1;
  int bid = blockIdx.x;
  const int nwg = gridDim.x;               // 2560, %8==0
  bid = (bid & 7) * (nwg >> 3) + (bid >> 3);
  const int k = bid >> 9;                  // 512 blocks per k-slice
  const int rem = bid & 511;
  const int mt = rem >> 2, nt = rem & 3;   // consecutive bids share mt -> L2
  const size_t m0 = (size_t)mt * 128;
  const int n0 = nt * 128;
  const int lrow = l & 15;
  const int lk = (l >> 4) * 8;
  const f16* Pk = Wbig + (size_t)k * 512 * 512;

  f32x4 acc[4][4] = {};

  // ---- phase 1: topics(b,k,:) x Ua  (fp32 A, reg-staged convert)
  for (int k0 = 0; k0 < 512; k0 += 32) {
    #pragma unroll
    for (int p = 0; p < 2; ++p) {
      int c = p * 256 + t;
      int row = c >> 2, seg = c & 3;
      gload_lds16(Ua_h + (size_t)(n0 + row) * 512 + k0 + seg * 8,
                  (char*)Bs + c * 16);
    }
    #pragma unroll
    for (int p = 0; p < 4; ++p) {
      int c = p * 256 + t;
      int row = c >> 3, seg = c & 7;
      const float4 v = *(const float4*)(
          topics + ((m0 + row) * K_SZ + k) * E_SZ + k0 + seg * 4);
      union { f16 h[4]; uint2 u; } cv;
      cv.h[0] = (f16)v.x; cv.h[1] = (f16)v.y;
      cv.h[2] = (f16)v.z; cv.h[3] = (f16)v.w;
      *(uint2*)((char*)As + row * 64 + seg * 8) = cv.u;
    }
    __syncthreads();

    f16x8 af[4], bf[4];
    #pragma unroll
    for (int mi = 0; mi < 4; ++mi)
      af[mi] = *(const f16x8*)(As + (wm * 64 + mi * 16 + lrow) * 32 + lk);
    #pragma unroll
    for (int ni = 0; ni < 4; ++ni)
      bf[ni] = *(const f16x8*)(Bs + (wn * 64 + ni * 16 + lrow) * 32 + lk);
    #pragma unroll
    for (int mi = 0; mi < 4; ++mi)
      #pragma unroll
      for (int ni = 0; ni < 4; ++ni)
        acc[mi][ni] = __builtin_amdgcn_mfma_f32_16x16x32_f16(
            af[mi], bf[ni], acc[mi][ni], 0, 0, 0);
    __syncthreads();
  }

  // ---- phase 2: q0(b,:) x P_k  (f16 A via global_load_lds)
  for (int k0 = 0; k0 < 512; k0 += 32) {
    #pragma unroll
    for (int p = 0; p < 2; ++p) {
      int c = p * 256 + t;
      int row = c >> 2, seg = c & 3;
      gload_lds16(Pk + (size_t)(n0 + row) * 512 + k0 + seg * 8,
                  (char*)Bs + c * 16);
      gload_lds16(q0h + (m0 + row) * (size_t)H_SZ + k0 + seg * 8,
                  (char*)As + c * 16);
    }
    __syncthreads();

    f16x8 af[4], bf[4];
    #pragma unroll
    for (int mi = 0; mi < 4; ++mi)
      af[mi] = *(const f16x8*)(As + (wm * 64 + mi * 16 + lrow) * 32 + lk);
    #pragma unroll
    for (int ni = 0; ni < 4; ++ni)
      bf[ni] = *(const f16x8*)(Bs + (wn * 64 + ni * 16 + lrow) * 32 + lk);
    #pragma unroll
    for (int mi = 0; mi < 4; ++mi)
      #pragma unroll
      for (int ni = 0; ni < 4; ++ni)
        acc[mi][ni] = __builtin_amdgcn_mfma_f32_16x16x32_f16(
            af[mi], bf[ni], acc[mi][ni], 0, 0, 0);
    __syncthreads();
  }

  // ---- epilogue: partial score = sum_h va[h]*tanh(X) over 128 cols.
  // C/D layout: col = n0 + wn*64 + ni*16 + (l&15); row = wm*64+mi*16+(l>>4)*4+j
  const int colbase = n0 + wn * 64 + lrow;
  float va4[4];
  #pragma unroll
  for (int ni = 0; ni < 4; ++ni) va4[ni] = va_w[colbase + ni * 16];

  #pragma unroll
  for (int mi = 0; mi < 4; ++mi) {
    #pragma unroll
    for (int j = 0; j < 4; ++j) {
      float s = 0.f;
      #pragma unroll
      for (int ni = 0; ni < 4; ++ni)
        s += va4[ni] * fast_tanh(acc[mi][ni][j]);
      #pragma unroll
      for (int m = 1; m < 16; m <<= 1) s += __shfl_xor(s, m);
      if (lrow == 0) {
        int row = (int)m0 + wm * 64 + mi * 16 + ((l >> 4) << 2) + j;
        partials[(size_t)(nt * 2 + wn) * (K_SZ * B_SZ) + k * B_SZ + row] = s;
      }
    }
  }
}

// ---------------------------------------------------------------------------
// scores (from 8 partial slices) -> softmax -> mt. One wave per b row.
__global__ __launch_bounds__(256)
void finalize2(const float* __restrict__ partials,
               const float* __restrict__ topics, const float* __restrict__ cov,
               const float* __restrict__ va_b, float* __restrict__ out) {
  const int wid = threadIdx.x >> 6, l = threadIdx.x & 63;
  const size_t b = (size_t)blockIdx.x * 4 + wid;
  const float vb = va_b[0];

  float s[K_SZ];
  #pragma unroll
  for (int k = 0; k < K_SZ; ++k) {
    float raw = 0.f;
    #pragma unroll
    for (int sl = 0; sl < 8; ++sl)
      raw += partials[(size_t)sl * (K_SZ * B_SZ) + k * B_SZ + b];
    s[k] = (raw + vb) * cov[b * K_SZ + k];
  }

  // softmax over K
  float m = s[0];
  #pragma unroll
  for (int k = 1; k < K_SZ; ++k) m = fmaxf(m, s[k]);
  float a[K_SZ], d = 0.f;
  #pragma unroll
  for (int k = 0; k < K_SZ; ++k) { a[k] = __expf(s[k] - m); d += a[k]; }
  float inv = 1.f / d;
  #pragma unroll
  for (int k = 0; k < K_SZ; ++k) a[k] *= inv;

  // mt = sum_k a[k] * topics[b,k,:]
  float acc0[4] = {}, acc1[4] = {};
  #pragma unroll
  for (int k = 0; k < K_SZ; ++k) {
    const float* tp = topics + (b * K_SZ + k) * E_SZ + l * 8;
    float4 t0 = *(const float4*)tp;
    float4 t1 = *(const float4*)(tp + 4);
    acc0[0] += a[k] * t0.x; acc0[1] += a[k] * t0.y;
    acc0[2] += a[k] * t0.z; acc0[3] += a[k] * t0.w;
    acc1[0] += a[k] * t1.x; acc1[1] += a[k] * t1.y;
    acc1[2] += a[k] * t1.z; acc1[3] += a[k] * t1.w;
  }
  float* mo = out + b * E_SZ + l * 8;
  *(float4*)mo       = make_float4(acc0[0], acc0[1], acc0[2], acc0[3]);
  *(float4*)(mo + 4) = make_float4(acc1[0], acc1[1], acc1[2], acc1[3]);
  if (l < K_SZ) {
    float av = (l == 0) ? a[0] : (l == 1) ? a[1] : (l == 2) ? a[2]
               : (l == 3) ? a[3] : a[4];
    out[(size_t)B_SZ * E_SZ + b * K_SZ + l] = av;
  }
}

// ---------------------------------------------------------------------------
extern "C" void kernel_launch(void* const* d_in, const int* in_sizes, int n_in,
                              void* d_out, int out_size, void* d_ws, size_t ws_size,
                              hipStream_t stream) {
  const float* query  = (const float*)d_in[0];
  const float* topics = (const float*)d_in[1];
  const float* cov    = (const float*)d_in[2];
  const float* Ua     = (const float*)d_in[3];
  const float* Wa     = (const float*)d_in[4];
  const float* va_w   = (const float*)d_in[5];
  const float* va_b   = (const float*)d_in[6];
  float* out = (float*)d_out;

  char* ws = (char*)d_ws;
  size_t off = 0;
  auto alloc = [&](size_t bytes) -> char* {
    char* p = ws + off;
    off += (bytes + 255) & ~(size_t)255;
    return p;
  };
  f16* q0h   = (f16*)alloc((size_t)B_SZ * H_SZ * 2);             // 16.8 MB
  f16* Ua_h  = (f16*)alloc((size_t)H_SZ * E_SZ * 2);             // 0.5 MB
  f16* WaT   = (f16*)alloc((size_t)H_SZ * H_SZ * 2);             // 0.5 MB
  f16* Wbig  = (f16*)alloc((size_t)K_SZ * H_SZ * H_SZ * 2);      // 2.6 MB
  float* partials = (float*)alloc((size_t)8 * K_SZ * B_SZ * 4);  // 2.6 MB

  // prep: Wa->f16 (Wbig block 0 = Wa^1), Ua->f16, Wa^T->f16
  prep_weights<<<512, 256, 0, stream>>>(Wa, Ua, Wbig, Ua_h, WaT);
  // query -> f16
  cvt_kernel<<<B_SZ * H_SZ / 8 / 256, 256, 0, stream>>>(query, q0h,
                                                        B_SZ * H_SZ / 8);
  // Wa powers: M_j = M_{j-1} @ Wa  (gemm_bt with W = WaT)
  for (int j = 1; j < K_SZ; ++j)
    gemm_bt<<<16, 256, 0, stream>>>(Wbig + (size_t)(j - 1) * H_SZ * H_SZ, WaT,
                                    Wbig + (size_t)j * H_SZ * H_SZ, H_SZ,
                                    H_SZ, 4);
  // fused q+pk GEMM with tanh*va partial-score epilogue
  fused_score_gemm<<<K_SZ * (B_SZ / 128) * (H_SZ / 128), 256, 0, stream>>>(
      topics, q0h, Ua_h, Wbig, va_w, partials);
  // softmax + mt
  finalize2<<<B_SZ / 4, 256, 0, stream>>>(partials, topics, cov, va_b, out);
}